// Round 7
// baseline (1692.064 us; speedup 1.0000x reference)
//
#include <hip/hip_runtime.h>
#include <math.h>

typedef unsigned short u16;
typedef unsigned int   u32;
typedef __attribute__((ext_vector_type(8))) short    bf16x8; // 8 bf16 (4 VGPRs)
typedef __attribute__((ext_vector_type(8))) _Float16 f16x8;  // 8 fp16 (4 VGPRs)
typedef __attribute__((ext_vector_type(4))) float    f32x4;

__device__ __forceinline__ u16 f2bf(float f) {
  u32 u = __float_as_uint(f);
  u = (u + 0x7FFFu + ((u >> 16) & 1u)) >> 16;
  return (u16)u;
}
__device__ __forceinline__ float bf2f(u16 s) {
  return __uint_as_float(((u32)s) << 16);
}

// fp16 split: v ≈ hi + lo/2048, lo = fp16((v-hi)*2048) stays in normal range.
__device__ __forceinline__ void splitF16(float v, u16& hi, u16& lo) {
  _Float16 h = (_Float16)v;
  _Float16 l = (_Float16)((v - (float)h) * 2048.0f);
  hi = __builtin_bit_cast(u16, h);
  lo = __builtin_bit_cast(u16, l);
}

#define GLOAD16(g, l)                                                         \
  __builtin_amdgcn_global_load_lds(                                           \
      (const __attribute__((address_space(1))) void*)(g),                     \
      (__attribute__((address_space(3))) void*)(l), 16, 0, 0)

// ---------------------------------------------------------------------------
// QKV projection (fp32 VALU): acc[m,n] = sum_c img[b,c,s]*W[n,c].
// EPI 0: fp32 out. EPI 1: split-fp16 out (hi, lo*2048 planes).
template<int EPI>
__global__ __launch_bounds__(256, 2)
void qkv_proj(const float* __restrict__ img, const float* __restrict__ W,
              float* __restrict__ OutF, u16* __restrict__ OutHi,
              u16* __restrict__ OutLo)
{
  __shared__ float As[16][128];
  __shared__ float Bs[16][128];
  const int tid = threadIdx.x;
  const int m0 = blockIdx.x * 128;
  const int n0 = blockIdx.y * 128;
  const int b  = m0 >> 12;
  const int s0 = m0 & 4095;
  const int tx = tid & 15, ty = tid >> 4;

  float acc[8][8];
  #pragma unroll
  for (int i = 0; i < 8; ++i)
    #pragma unroll
    for (int j = 0; j < 8; ++j) acc[i][j] = 0.0f;

  const int mm = tid & 127;
  const int kb = (tid >> 7) << 3;
  const int row = tid >> 1;
  const int kq  = (tid & 1) << 3;

  for (int k0 = 0; k0 < 256; k0 += 16) {
    #pragma unroll
    for (int i = 0; i < 8; ++i)
      As[kb + i][mm] = img[(size_t)(b * 256 + k0 + kb + i) * 4096 + s0 + mm];
    float4 b0 = *(const float4*)&W[(size_t)(n0 + row) * 256 + k0 + kq];
    float4 b1 = *(const float4*)&W[(size_t)(n0 + row) * 256 + k0 + kq + 4];
    Bs[kq + 0][row] = b0.x; Bs[kq + 1][row] = b0.y;
    Bs[kq + 2][row] = b0.z; Bs[kq + 3][row] = b0.w;
    Bs[kq + 4][row] = b1.x; Bs[kq + 5][row] = b1.y;
    Bs[kq + 6][row] = b1.z; Bs[kq + 7][row] = b1.w;
    __syncthreads();
    #pragma unroll
    for (int kk = 0; kk < 16; ++kk) {
      float a[8], bb[8];
      *(float4*)&a[0]  = *(const float4*)&As[kk][ty * 8];
      *(float4*)&a[4]  = *(const float4*)&As[kk][ty * 8 + 4];
      *(float4*)&bb[0] = *(const float4*)&Bs[kk][tx * 8];
      *(float4*)&bb[4] = *(const float4*)&Bs[kk][tx * 8 + 4];
      #pragma unroll
      for (int i = 0; i < 8; ++i)
        #pragma unroll
        for (int j = 0; j < 8; ++j)
          acc[i][j] = fmaf(a[i], bb[j], acc[i][j]);
    }
    __syncthreads();
  }

  #pragma unroll
  for (int i = 0; i < 8; ++i) {
    size_t base = (size_t)(m0 + ty * 8 + i) * 768 + n0 + tx * 8;
    if (EPI == 0) {
      *(float4*)&OutF[base]     = make_float4(acc[i][0], acc[i][1], acc[i][2], acc[i][3]);
      *(float4*)&OutF[base + 4] = make_float4(acc[i][4], acc[i][5], acc[i][6], acc[i][7]);
    } else {
      union { u16 u[8]; uint4 v; } ph, pl;
      #pragma unroll
      for (int j = 0; j < 8; ++j)
        splitF16(acc[i][j], ph.u[j], pl.u[j]);
      *(uint4*)&OutHi[base] = ph.v;
      *(uint4*)&OutLo[base] = pl.v;
    }
  }
}

// ---------------------------------------------------------------------------
// p-slice GEMM (MFMA, fp16-split = near-fp32):
// p = ((qh·kL + qL·kh)·2^-11 + qh·kh) / sqrt(768).  M=N=4096, 3 segs x K=256.
__global__ __launch_bounds__(256, 2)
void pgemm_mfma(const u16* __restrict__ Qhi, const u16* __restrict__ Qlo,
                const u16* __restrict__ Khi, const u16* __restrict__ Klo,
                float* __restrict__ P, int bsel, int hsel)
{
  __shared__ u16 As[128 * 64];
  __shared__ u16 Bs[128 * 64];
  const int tid = threadIdx.x;
  const int l = tid & 63;
  const int w = tid >> 6;
  const int wm = w >> 1, wn = w & 1;
  const int m0 = blockIdx.x * 128;
  const int n0 = blockIdx.y * 128;
  const size_t base = (size_t)bsel * 4096 * 768 + hsel * 256;

  f32x4 acc[4][4];
  #pragma unroll
  for (int mf = 0; mf < 4; ++mf)
    #pragma unroll
    for (int nf = 0; nf < 4; ++nf) {
      f32x4 z = {0.f, 0.f, 0.f, 0.f};
      acc[mf][nf] = z;
    }

  const int srow = tid >> 3;
  const int swz  = (tid & 7) ^ (srow & 7);

  for (int t = 0; t < 12; ++t) {
    const u16* Aseg = (t >= 4 && t < 8) ? Qlo : Qhi;
    const u16* Bseg = (t < 4) ? Klo : Khi;
    const int ci0 = (t & 3) << 6;
    #pragma unroll
    for (int i = 0; i < 4; ++i) {
      const int pix = i * 32 + srow;
      GLOAD16(Aseg + base + (size_t)(m0 + pix) * 768 + ci0 + swz * 8,
              As + (i * 32 + 8 * w) * 64);
      GLOAD16(Bseg + base + (size_t)(n0 + pix) * 768 + ci0 + swz * 8,
              Bs + (i * 32 + 8 * w) * 64);
    }
    __syncthreads();

    #pragma unroll
    for (int kk = 0; kk < 2; ++kk) {
      f16x8 av[4], bv[4];
      const int slot = kk * 4 + (l >> 4);
      #pragma unroll
      for (int mf = 0; mf < 4; ++mf) {
        int m = wm * 64 + mf * 16 + (l & 15);
        av[mf] = *(const f16x8*)((const char*)As + m * 128 + ((slot ^ (m & 7)) << 4));
      }
      #pragma unroll
      for (int nf = 0; nf < 4; ++nf) {
        int n = wn * 64 + nf * 16 + (l & 15);
        bv[nf] = *(const f16x8*)((const char*)Bs + n * 128 + ((slot ^ (n & 7)) << 4));
      }
      #pragma unroll
      for (int mf = 0; mf < 4; ++mf)
        #pragma unroll
        for (int nf = 0; nf < 4; ++nf)
          acc[mf][nf] = __builtin_amdgcn_mfma_f32_16x16x32_f16(
              av[mf], bv[nf], acc[mf][nf], 0, 0, 0);
    }
    __syncthreads();

    if (t == 7) {
      #pragma unroll
      for (int mf = 0; mf < 4; ++mf)
        #pragma unroll
        for (int nf = 0; nf < 4; ++nf)
          acc[mf][nf] *= (1.0f / 2048.0f);
    }
  }

  const float scale = 0.036084391824351615f;   // 1/sqrt(768)
  #pragma unroll
  for (int mf = 0; mf < 4; ++mf)
    #pragma unroll
    for (int nf = 0; nf < 4; ++nf) {
      const int col = n0 + wn * 64 + nf * 16 + (l & 15);
      #pragma unroll
      for (int j = 0; j < 4; ++j) {
        const int row = m0 + wm * 64 + mf * 16 + (l >> 4) * 4 + j;
        P[(size_t)row * 4096 + col] = acc[mf][nf][j] * scale;
      }
    }
}

// ---------------------------------------------------------------------------
// Per-row top-16 on one p slice; one wave per row.
// Tier 1 (gap > THRESH): softmax over top-8, write attn + tkb pairs, flag=0.
// Tier 2 (tight gap):    write 16 candidate indices into tkb, flag=1.
__global__ __launch_bounds__(256)
void topk_softmax(const float* __restrict__ p, float* __restrict__ attn,
                  float* __restrict__ tkb, u32* __restrict__ flagArr, int slice)
{
  const int wave = threadIdx.x >> 6;
  const int lane = threadIdx.x & 63;
  const int r = blockIdx.x * 4 + wave;
  const float4* row4 = (const float4*)(p + (size_t)r * 4096);

  float v[8];
  int   id[8];
  #pragma unroll
  for (int t = 0; t < 8; ++t) { v[t] = -INFINITY; id[t] = -1; }

#define TK_INS(val, col)                                                    \
  if ((val) > v[7]) {                                                       \
    v[7] = (val); id[7] = (col);                                            \
    _Pragma("unroll")                                                       \
    for (int t = 7; t >= 1; --t) {                                          \
      if (v[t] > v[t-1]) {                                                  \
        float tv = v[t]; v[t] = v[t-1]; v[t-1] = tv;                        \
        int ti = id[t]; id[t] = id[t-1]; id[t-1] = ti;                      \
      }                                                                     \
    }                                                                       \
  }

  for (int i = 0; i < 16; ++i) {
    float4 q = row4[i * 64 + lane];
    int cb = (i * 64 + lane) * 4;
    TK_INS(q.x, cb + 0)
    TK_INS(q.y, cb + 1)
    TK_INS(q.z, cb + 2)
    TK_INS(q.w, cb + 3)
  }
#undef TK_INS

  // Merge 64 sorted per-lane lists -> global top-16 (all lanes get copies).
  float topv[16];
  int   topi[16];
  int head = 0;
  #pragma unroll
  for (int t = 0; t < 16; ++t) {
    float cand = (head < 8) ? v[head] : -INFINITY;
    float mx = cand; int src = lane;
    #pragma unroll
    for (int off = 32; off >= 1; off >>= 1) {
      float om = __shfl_xor(mx, off);
      int   os = __shfl_xor(src, off);
      if (om > mx || (om == mx && os < src)) { mx = om; src = os; }
    }
    int ci = (head < 8) ? id[head] : -1;
    int wi = __shfl(ci, src);
    if (lane == src) head++;
    topv[t] = mx; topi[t] = wi;
  }

  const float THRESH = 1e-4f;
  unsigned long long exh = __ballot(head >= 8);   // lane list exhausted (rare)
  const bool flagged = (topv[7] - topv[8] <= THRESH) || (exh != 0ULL);

  const size_t grow = (size_t)slice * 4096 + r;
  if (!flagged) {
    const float m0 = topv[0];
    float den = 0.0f;
    #pragma unroll
    for (int t = 0; t < 8; ++t) den += expf(topv[t] - m0);
    if (lane < 8) {
      float wgt = expf(topv[lane] - m0) / den;
      attn[grow * 4096 + topi[lane]] = wgt;
      tkb[grow * 16 + lane * 2]     = __int_as_float(topi[lane]);
      tkb[grow * 16 + lane * 2 + 1] = wgt;
    }
    if (lane == 0) flagArr[grow] = 0;
  } else {
    if (lane < 16) tkb[grow * 16 + lane] = __int_as_float(topi[lane]);
    if (lane == 0) flagArr[grow] = 1;
  }
}

// ---------------------------------------------------------------------------
// Tier-2: exact (float64) rescoring of the 16 candidates for flagged rows,
// recomputed from raw inputs (matches a float64 reference's selection).
// score_t = (Wq_h x_col)ᵀ (Wk_h ref_col_t) / sqrt(768)
//         = u · ref_col_t,  u[c2] = sum_c qd[c] Wk[h*256+c][c2]
__global__ __launch_bounds__(256)
void tier2_fix(const float* __restrict__ x, const float* __restrict__ ref,
               const float* __restrict__ Wq, const float* __restrict__ Wk,
               const u32* __restrict__ flagArr, float* __restrict__ tkb,
               float* __restrict__ attn)
{
  const int row = blockIdx.x;                // slice*4096 + s
  if (flagArr[row] == 0) return;
  const int slice = row >> 12;
  const int s = row & 4095;
  const int b = slice / 3, h = slice % 3;
  const int tid = threadIdx.x;

  __shared__ double redbuf[256];
  __shared__ double qd_s[256];
  __shared__ double u_s[256];
  __shared__ float  xcol[256];
  __shared__ double scores[16];
  __shared__ int    cand[16];

  if (tid < 16) cand[tid] = __float_as_int(tkb[(size_t)row * 16 + tid]);
  xcol[tid] = x[((size_t)(b * 256 + tid) << 12) + s];
  __syncthreads();

  // qd[c] = sum_c2 Wq[h*256+c][c2] * xcol[c2]
  {
    const float* wr = Wq + (size_t)(h * 256 + tid) * 256;
    double acc = 0.0;
    for (int c2 = 0; c2 < 256; ++c2)
      acc = fma((double)wr[c2], (double)xcol[c2], acc);
    qd_s[tid] = acc;
  }
  __syncthreads();

  // u[c2] = sum_c qd[c] * Wk[h*256+c][c2]   (coalesced in c2)
  {
    double acc = 0.0;
    for (int c = 0; c < 256; ++c)
      acc = fma(qd_s[c], (double)Wk[(size_t)(h * 256 + c) * 256 + tid], acc);
    u_s[tid] = acc;
  }
  __syncthreads();

  const double scl = 1.0 / sqrt(768.0);
  for (int t = 0; t < 16; ++t) {
    int ks = cand[t];
    redbuf[tid] = u_s[tid] * (double)ref[((size_t)(b * 256 + tid) << 12) + ks];
    __syncthreads();
    for (int off = 128; off >= 1; off >>= 1) {
      if (tid < off) redbuf[tid] += redbuf[tid + off];
      __syncthreads();
    }
    if (tid == 0) scores[t] = redbuf[0] * scl;
    __syncthreads();
  }

  if (tid == 0) {
    int sel[16];
    for (int i = 0; i < 16; ++i) sel[i] = i;
    for (int i = 0; i < 8; ++i) {
      int best = i;
      for (int j = i + 1; j < 16; ++j)
        if (scores[sel[j]] > scores[sel[best]]) best = j;
      int tmp = sel[i]; sel[i] = sel[best]; sel[best] = tmp;
    }
    double m = scores[sel[0]];
    double e[8], den = 0.0;
    for (int i = 0; i < 8; ++i) { e[i] = exp(scores[sel[i]] - m); den += e[i]; }
    for (int i = 0; i < 8; ++i) {
      int idx = cand[sel[i]];
      float wgt = (float)(e[i] / den);
      attn[(size_t)row * 4096 + idx] = wgt;
      tkb[(size_t)row * 16 + i * 2]     = __int_as_float(idx);
      tkb[(size_t)row * 16 + i * 2 + 1] = wgt;
    }
  }
}

// ---------------------------------------------------------------------------
// Implicit-GEMM 3x3 conv on matrix cores, split-bf16 (fp32-equivalent).
template<int EPI>
__global__ __launch_bounds__(256, 2)
void conv_mfma(const u16* __restrict__ inHi, const u16* __restrict__ inLo,
               const u16* __restrict__ WtHi, const u16* __restrict__ WtLo,
               const float* __restrict__ bias, const float* __restrict__ resid,
               float* __restrict__ outF, u16* __restrict__ outHi,
               u16* __restrict__ outLo)
{
  __shared__ u16 As[128 * 64];
  __shared__ u16 Bs[128 * 64];
  const int tid = threadIdx.x;
  const int l = tid & 63;
  const int w = tid >> 6;
  const int wm = w >> 1, wn = w & 1;
  const int m0 = blockIdx.x * 128;
  const int n0 = blockIdx.y * 128;
  const int bimg = m0 >> 12;
  const int y0 = (m0 & 4095) >> 6;

  f32x4 acc[4][4];
  #pragma unroll
  for (int mf = 0; mf < 4; ++mf)
    #pragma unroll
    for (int nf = 0; nf < 4; ++nf) {
      f32x4 z = {0.f, 0.f, 0.f, 0.f};
      acc[mf][nf] = z;
    }

  const int srow = tid >> 3;
  const int swz  = (tid & 7) ^ (srow & 7);

  for (int seg = 0; seg < 3; ++seg) {
    const u16* Ain = (seg < 2) ? inHi : inLo;
    const u16* Bw  = (seg == 1) ? WtLo : WtHi;
    for (int d = 0; d < 9; ++d) {
      const int dy = d / 3, dx = d - dy * 3;
      for (int cb = 0; cb < 4; ++cb) {
        const int ci0 = cb << 6;
        #pragma unroll
        for (int i = 0; i < 4; ++i) {
          const int pix = i * 32 + srow;
          const int r = pix >> 6, xx = pix & 63;
          GLOAD16(Ain + ((size_t)((bimg * 66 + y0 + r + dy) * 66) + dx + xx) * 256
                      + ci0 + swz * 8,
                  As + (i * 32 + 8 * w) * 64);
          const int co = i * 32 + srow;
          GLOAD16(Bw + (size_t)(n0 + co) * 2304 + d * 256 + ci0 + swz * 8,
                  Bs + (i * 32 + 8 * w) * 64);
        }
        __syncthreads();

        #pragma unroll
        for (int kk = 0; kk < 2; ++kk) {
          bf16x8 av[4], bv[4];
          const int slot = kk * 4 + (l >> 4);
          #pragma unroll
          for (int mf = 0; mf < 4; ++mf) {
            int m = wm * 64 + mf * 16 + (l & 15);
            av[mf] = *(const bf16x8*)((const char*)As + m * 128 + ((slot ^ (m & 7)) << 4));
          }
          #pragma unroll
          for (int nf = 0; nf < 4; ++nf) {
            int n = wn * 64 + nf * 16 + (l & 15);
            bv[nf] = *(const bf16x8*)((const char*)Bs + n * 128 + ((slot ^ (n & 7)) << 4));
          }
          #pragma unroll
          for (int mf = 0; mf < 4; ++mf)
            #pragma unroll
            for (int nf = 0; nf < 4; ++nf)
              acc[mf][nf] = __builtin_amdgcn_mfma_f32_16x16x32_bf16(
                  av[mf], bv[nf], acc[mf][nf], 0, 0, 0);
        }
        __syncthreads();
      }
    }
  }

  #pragma unroll
  for (int nf = 0; nf < 4; ++nf) {
    const int co = n0 + wn * 64 + nf * 16 + (l & 15);
    const float bvv = bias[co];
    #pragma unroll
    for (int mf = 0; mf < 4; ++mf) {
      #pragma unroll
      for (int j = 0; j < 4; ++j) {
        const int p = m0 + wm * 64 + mf * 16 + (l >> 4) * 4 + j;
        const int y = (p & 4095) >> 6, xx = p & 63;
        float v = acc[mf][nf][j] + bvv;
        if (EPI == 0) {
          v = (v > 0.f) ? 1.0507009873554805f * v
                        : 1.7580993408473766f * expm1f(v);
          size_t ad = ((size_t)((bimg * 66 + 1 + y) * 66) + 1 + xx) * 256 + co;
          u16 h = f2bf(v);
          outHi[ad] = h;
          outLo[ad] = f2bf(v - bf2f(h));
        } else {
          size_t ad = ((size_t)(bimg * 256 + co) << 12) + (y << 6) + xx;
          outF[ad] = v + resid[ad];
        }
      }
    }
  }
}

// ---------------------------------------------------------------------------
// Wo GEMM (fp32): h = read @ Wo^T + x -> split-bf16 padded channel-last.
__global__ __launch_bounds__(256, 2)
void gemm_wo(const float* __restrict__ A, const float* __restrict__ B,
             const float* __restrict__ xin, u16* __restrict__ hHi,
             u16* __restrict__ hLo)
{
  __shared__ float As[16][128];
  __shared__ float Bs[16][128];
  const int tid = threadIdx.x;
  const int m0 = blockIdx.x * 128;
  const int n0 = blockIdx.y * 128;
  const int tx = tid & 15, ty = tid >> 4;

  float acc[8][8];
  #pragma unroll
  for (int i = 0; i < 8; ++i)
    #pragma unroll
    for (int j = 0; j < 8; ++j) acc[i][j] = 0.0f;

  const int row = tid >> 1;
  const int kq  = (tid & 1) << 3;

  for (int k0 = 0; k0 < 768; k0 += 16) {
    float4 a0 = *(const float4*)&A[(size_t)(m0 + row) * 768 + k0 + kq];
    float4 a1 = *(const float4*)&A[(size_t)(m0 + row) * 768 + k0 + kq + 4];
    As[kq + 0][row] = a0.x; As[kq + 1][row] = a0.y;
    As[kq + 2][row] = a0.z; As[kq + 3][row] = a0.w;
    As[kq + 4][row] = a1.x; As[kq + 5][row] = a1.y;
    As[kq + 6][row] = a1.z; As[kq + 7][row] = a1.w;
    float4 b0 = *(const float4*)&B[(size_t)(n0 + row) * 768 + k0 + kq];
    float4 b1 = *(const float4*)&B[(size_t)(n0 + row) * 768 + k0 + kq + 4];
    Bs[kq + 0][row] = b0.x; Bs[kq + 1][row] = b0.y;
    Bs[kq + 2][row] = b0.z; Bs[kq + 3][row] = b0.w;
    Bs[kq + 4][row] = b1.x; Bs[kq + 5][row] = b1.y;
    Bs[kq + 6][row] = b1.z; Bs[kq + 7][row] = b1.w;
    __syncthreads();
    #pragma unroll
    for (int kk = 0; kk < 16; ++kk) {
      float a[8], bb[8];
      *(float4*)&a[0]  = *(const float4*)&As[kk][ty * 8];
      *(float4*)&a[4]  = *(const float4*)&As[kk][ty * 8 + 4];
      *(float4*)&bb[0] = *(const float4*)&Bs[kk][tx * 8];
      *(float4*)&bb[4] = *(const float4*)&Bs[kk][tx * 8 + 4];
      #pragma unroll
      for (int i = 0; i < 8; ++i)
        #pragma unroll
        for (int j = 0; j < 8; ++j)
          acc[i][j] = fmaf(a[i], bb[j], acc[i][j]);
    }
    __syncthreads();
  }

  #pragma unroll
  for (int i = 0; i < 8; ++i) {
    const int m = m0 + ty * 8 + i;
    const int b = m >> 12, s = m & 4095;
    const int y = s >> 6, xx = s & 63;
    union { u16 u[8]; uint4 v; } ph, pl;
    #pragma unroll
    for (int j = 0; j < 8; ++j) {
      const int n = n0 + tx * 8 + j;
      float val = acc[i][j] + xin[((size_t)(b * 256 + n) << 12) + s];
      u16 h = f2bf(val);
      ph.u[j] = h;
      pl.u[j] = f2bf(val - bf2f(h));
    }
    size_t ad = ((size_t)((b * 66 + 1 + y) * 66) + 1 + xx) * 256 + n0 + tx * 8;
    *(uint4*)&hHi[ad] = ph.v;
    *(uint4*)&hLo[ad] = pl.v;
  }
}

// ---------------------------------------------------------------------------
// Sparse PV: read[b,s,h*256+c] = sum_{t<8} w_t * V[b, idx_t, h*256+c]
__global__ __launch_bounds__(256)
void read_gather(const float* __restrict__ V, const float* __restrict__ tkb,
                 float* __restrict__ readO)
{
  const int gr = blockIdx.x;
  const int c  = threadIdx.x;
  const int bh = gr >> 12;
  const int s  = gr & 4095;
  const int b  = bh / 3;
  const int h  = bh % 3;

  __shared__ float wv[8];
  __shared__ int   wi[8];
  if (threadIdx.x < 8) {
    wi[threadIdx.x] = __float_as_int(tkb[(size_t)gr * 16 + threadIdx.x * 2]);
    wv[threadIdx.x] = tkb[(size_t)gr * 16 + threadIdx.x * 2 + 1];
  }
  __syncthreads();

  const float* Vb = V + (size_t)b * 4096 * 768 + h * 256 + c;
  float acc = 0.0f;
  #pragma unroll
  for (int t = 0; t < 8; ++t)
    acc = fmaf(wv[t], Vb[(size_t)wi[t] * 768], acc);
  readO[((size_t)(b * 4096 + s)) * 768 + h * 256 + c] = acc;
}

// ---------------------------------------------------------------------------
// Conv weight prep: split-bf16 Wt[co][d][ci] <- w[co][ci][d] fp32.
__global__ __launch_bounds__(256)
void prep_wt(const float* __restrict__ w1, const float* __restrict__ w2,
             u16* __restrict__ W1h, u16* __restrict__ W1l,
             u16* __restrict__ W2h, u16* __restrict__ W2l)
{
  const int idx = blockIdx.x * 256 + threadIdx.x;
  if (idx >= 256 * 2304) return;
  const int co = idx / 2304;
  const int rem = idx - co * 2304;
  const int d = rem >> 8, ci = rem & 255;
  const int src = (co * 256 + ci) * 9 + d;
  float v1 = w1[src], v2 = w2[src];
  u16 h1 = f2bf(v1), h2 = f2bf(v2);
  W1h[idx] = h1; W1l[idx] = f2bf(v1 - bf2f(h1));
  W2h[idx] = h2; W2l[idx] = f2bf(v2 - bf2f(h2));
}

// ---------------------------------------------------------------------------
extern "C" void kernel_launch(void* const* d_in, const int* in_sizes, int n_in,
                              void* d_out, int out_size, void* d_ws, size_t ws_size,
                              hipStream_t stream)
{
  const float* x   = (const float*)d_in[0];
  const float* ref = (const float*)d_in[1];
  const float* Wq  = (const float*)d_in[2];
  const float* Wk  = (const float*)d_in[3];
  const float* Wv  = (const float*)d_in[4];
  const float* Wo  = (const float*)d_in[5];
  const float* c1w = (const float*)d_in[6];
  const float* c1b = (const float*)d_in[7];
  const float* c2w = (const float*)d_in[8];
  const float* c2b = (const float*)d_in[9];

  float* out  = (float*)d_out;                 // [4,256,64,64]
  float* attn = out + 4194304;                 // [12,4096,4096]
  float* ws   = (float*)d_ws;

  u16*   Qhi = (u16*)ws;                       // fp16 planes, 6.29M f32 each
  u16*   Qlo = (u16*)(ws + 6291456);
  u16*   Khi = (u16*)(ws + 12582912);
  u16*   Klo = (u16*)(ws + 18874368);
  float* Vb  = ws + 25165824;                  // 12.58M f32
  float* P   = ws + 37748736;                  // 16.78M f32 (one slice)
  float* tkb = ws + 54525952;                  // 49152*16 f32
  u32*   flagArr = (u32*)(ws + 55312384);      // 49152 u32
  float* rd  = P;                              // alias (after all slices)

  u16* hHi  = (u16*)ws;                        // padded conv act planes
  u16* hLo  = (u16*)(ws + 2230272);
  u16* f1Hi = (u16*)(ws + 6291456);
  u16* f1Lo = (u16*)(ws + 8521728);
  u16* W1h = (u16*)(ws + 12582912);            // split conv weights
  u16* W1l = (u16*)(ws + 12877824);
  u16* W2h = (u16*)(ws + 13172736);
  u16* W2l = (u16*)(ws + 13467648);

  dim3 blk(256);

  // Zero the sparse attn_map output region (805 MB).
  hipMemsetAsync(attn, 0, (size_t)201326592 * 4, stream);

  // Projections: Q,K split fp16 hi/lo; V fp32.
  qkv_proj<1><<<dim3(128, 6), blk, 0, stream>>>(x,   Wq, nullptr, Qhi, Qlo);
  qkv_proj<1><<<dim3(128, 6), blk, 0, stream>>>(ref, Wk, nullptr, Khi, Klo);
  qkv_proj<0><<<dim3(128, 6), blk, 0, stream>>>(ref, Wv, Vb, nullptr, nullptr);

  // Per (b,head) slice: MFMA p-GEMM, then tiered top-k.
  for (int bh = 0; bh < 12; ++bh) {
    pgemm_mfma<<<dim3(32, 32), blk, 0, stream>>>(Qhi, Qlo, Khi, Klo, P,
                                                 bh / 3, bh % 3);
    topk_softmax<<<dim3(1024), blk, 0, stream>>>(P, attn, tkb, flagArr, bh);
  }

  // Tier-2 exact (f64) fix-up for tight-gap rows.
  tier2_fix<<<dim3(49152), blk, 0, stream>>>(x, ref, Wq, Wk, flagArr, tkb, attn);

  // Sparse PV gather -> read [B,S,768] (fp32)
  read_gather<<<dim3(49152), blk, 0, stream>>>(Vb, tkb, rd);

  // Zero padded conv activation buffers (halos must be 0 every call).
  hipMemsetAsync(hHi,  0, (size_t)4460544 * 2, stream);
  hipMemsetAsync(hLo,  0, (size_t)4460544 * 2, stream);
  hipMemsetAsync(f1Hi, 0, (size_t)4460544 * 2, stream);
  hipMemsetAsync(f1Lo, 0, (size_t)4460544 * 2, stream);

  // attn_out = read @ Wo^T + x  -> split-bf16 padded channel-last h
  gemm_wo<<<dim3(128, 2), blk, 0, stream>>>(rd, Wo, x, hHi, hLo);

  // Conv weights -> split-bf16 [co][9][256]
  prep_wt<<<dim3(2304), blk, 0, stream>>>(c1w, c2w, W1h, W1l, W2h, W2l);

  // conv1 + SELU -> split-bf16 padded f1, conv2 + bias + x -> fp32 NCHW out
  conv_mfma<0><<<dim3(128, 2), blk, 0, stream>>>(hHi, hLo, W1h, W1l, c1b,
                                                 nullptr, nullptr, f1Hi, f1Lo);
  conv_mfma<1><<<dim3(128, 2), blk, 0, stream>>>(f1Hi, f1Lo, W2h, W2l, c2b,
                                                 x, out, nullptr, nullptr);
}

// Round 9
// 1360.473 us; speedup vs baseline: 1.2437x; 1.2437x over previous
//
#include <hip/hip_runtime.h>
#include <math.h>

typedef unsigned short u16;
typedef unsigned int   u32;
typedef __attribute__((ext_vector_type(8))) _Float16 f16x8;  // 8 fp16 (4 VGPRs)
typedef __attribute__((ext_vector_type(4))) float    f32x4;

// fp16 split: v ≈ hi + lo/2048, lo = fp16((v-hi)*2048) stays in normal range.
__device__ __forceinline__ void splitF16(float v, u16& hi, u16& lo) {
  _Float16 h = (_Float16)v;
  _Float16 l = (_Float16)((v - (float)h) * 2048.0f);
  hi = __builtin_bit_cast(u16, h);
  lo = __builtin_bit_cast(u16, l);
}
__device__ __forceinline__ u16 f16bits(float v) {
  _Float16 h = (_Float16)v;
  return __builtin_bit_cast(u16, h);
}

#define GLOAD16(g, l)                                                         \
  __builtin_amdgcn_global_load_lds(                                           \
      (const __attribute__((address_space(1))) void*)(g),                     \
      (__attribute__((address_space(3))) void*)(l), 16, 0, 0)

// ---------------------------------------------------------------------------
// Transpose+split: src [b][256][4096] f32 -> dH/dL [b*4096+s][256] fp16 planes.
__global__ __launch_bounds__(256)
void transpose_split(const float* __restrict__ src, u16* __restrict__ dH,
                     u16* __restrict__ dL)
{
  __shared__ float tile[32][65];
  const int b  = blockIdx.z;
  const int s0 = blockIdx.x * 64;
  const int c0 = blockIdx.y * 32;
  const int tid = threadIdx.x;
  const int sl = tid & 63;
  const int cl = (tid >> 6) * 8;
  #pragma unroll
  for (int i = 0; i < 8; ++i)
    tile[cl + i][sl] = src[((size_t)(b * 256 + c0 + cl + i) << 12) + s0 + sl];
  __syncthreads();
  const int sr = tid >> 2;
  const int cc = (tid & 3) * 8;
  union { u16 u[8]; uint4 v; } ph, pl;
  #pragma unroll
  for (int j = 0; j < 8; ++j)
    splitF16(tile[cc + j][sr], ph.u[j], pl.u[j]);
  size_t o = ((size_t)(b * 4096) + s0 + sr) * 256 + c0 + cc;
  *(uint4*)&dH[o] = ph.v;
  *(uint4*)&dL[o] = pl.v;
}

// ---------------------------------------------------------------------------
// Elementwise fp16 split of a weight matrix.
__global__ __launch_bounds__(256)
void split_plane(const float* __restrict__ src, u16* __restrict__ dH,
                 u16* __restrict__ dL, int n)
{
  int i = blockIdx.x * 256 + threadIdx.x;
  if (i < n) { u16 h, l; splitF16(src[i], h, l); dH[i] = h; dL[i] = l; }
}

// ---------------------------------------------------------------------------
// Conv weight prep: split-fp16 Wt[co][d][ci] <- w[co][ci][d] fp32 (both convs).
__global__ __launch_bounds__(256)
void prep_wt(const float* __restrict__ w1, const float* __restrict__ w2,
             u16* __restrict__ W1h, u16* __restrict__ W1l,
             u16* __restrict__ W2h, u16* __restrict__ W2l)
{
  const int idx = blockIdx.x * 256 + threadIdx.x;
  if (idx >= 256 * 2304) return;
  const int co = idx / 2304;
  const int rem = idx - co * 2304;
  const int d = rem >> 8, ci = rem & 255;
  const int src = (co * 256 + ci) * 9 + d;
  u16 h, l;
  splitF16(w1[src], h, l); W1h[idx] = h; W1l[idx] = l;
  splitF16(w2[src], h, l); W2h[idx] = h; W2l[idx] = l;
}

// ---------------------------------------------------------------------------
// Generic split-fp16 MFMA GEMM: C[m,n] = sum_k A[m,k]*B[n,k].
// NSEGS==3: Ah*Bl + Al*Bh (then *2^-11) + Ah*Bh  (fp32-equivalent)
// NSEGS==2: Ah*Bl (then *2^-11) + Ah*Bh          (A plain fp16, B exact)
// EPI 0: outU16 fp16 [m][768]. EPI 1: outF fp32 [m][768].
// EPI 2: h = acc + resid(NCHW) -> fp16 padded channel-last [b][66][66][256].
template<int KD, int NSEGS, int EPI>
__global__ __launch_bounds__(256, 2)
void gemm_split(const u16* __restrict__ Ah, const u16* __restrict__ Al,
                const u16* __restrict__ Bh, const u16* __restrict__ Bl,
                u16* __restrict__ outU, float* __restrict__ outF,
                const float* __restrict__ resid)
{
  __shared__ u16 As[128 * 64];
  __shared__ u16 Bs[128 * 64];
  const int tid = threadIdx.x;
  const int l = tid & 63;
  const int w = tid >> 6;
  const int wm = w >> 1, wn = w & 1;
  const int m0 = blockIdx.x * 128;
  const int n0 = blockIdx.y * 128;

  f32x4 acc[4][4];
  #pragma unroll
  for (int mf = 0; mf < 4; ++mf)
    #pragma unroll
    for (int nf = 0; nf < 4; ++nf) {
      f32x4 z = {0.f, 0.f, 0.f, 0.f};
      acc[mf][nf] = z;
    }

  const int srow = tid >> 3;
  const int swz  = (tid & 7) ^ (srow & 7);
  constexpr int TPS = KD / 64;

  for (int t = 0; t < NSEGS * TPS; ++t) {
    const int sg = t / TPS;
    const int ci0 = (t - sg * TPS) * 64;
    const u16* Ap;
    const u16* Bp;
    if (NSEGS == 3) { Ap = (sg == 1) ? Al : Ah; Bp = (sg == 0) ? Bl : Bh; }
    else            { Ap = Ah;                  Bp = (sg == 0) ? Bl : Bh; }
    #pragma unroll
    for (int i = 0; i < 4; ++i) {
      const int pix = i * 32 + srow;
      GLOAD16(Ap + (size_t)(m0 + pix) * KD + ci0 + swz * 8,
              As + (i * 32 + 8 * w) * 64);
      GLOAD16(Bp + (size_t)(n0 + pix) * KD + ci0 + swz * 8,
              Bs + (i * 32 + 8 * w) * 64);
    }
    __syncthreads();

    #pragma unroll
    for (int kk = 0; kk < 2; ++kk) {
      f16x8 av[4], bv[4];
      const int slot = kk * 4 + (l >> 4);
      #pragma unroll
      for (int mf = 0; mf < 4; ++mf) {
        int m = wm * 64 + mf * 16 + (l & 15);
        av[mf] = *(const f16x8*)((const char*)As + m * 128 + ((slot ^ (m & 7)) << 4));
      }
      #pragma unroll
      for (int nf = 0; nf < 4; ++nf) {
        int n = wn * 64 + nf * 16 + (l & 15);
        bv[nf] = *(const f16x8*)((const char*)Bs + n * 128 + ((slot ^ (n & 7)) << 4));
      }
      #pragma unroll
      for (int mf = 0; mf < 4; ++mf)
        #pragma unroll
        for (int nf = 0; nf < 4; ++nf)
          acc[mf][nf] = __builtin_amdgcn_mfma_f32_16x16x32_f16(
              av[mf], bv[nf], acc[mf][nf], 0, 0, 0);
    }
    __syncthreads();

    if (t == (NSEGS - 1) * TPS - 1) {
      #pragma unroll
      for (int mf = 0; mf < 4; ++mf)
        #pragma unroll
        for (int nf = 0; nf < 4; ++nf)
          acc[mf][nf] *= (1.0f / 2048.0f);
    }
  }

  #pragma unroll
  for (int mf = 0; mf < 4; ++mf)
    #pragma unroll
    for (int nf = 0; nf < 4; ++nf) {
      const int col = n0 + wn * 64 + nf * 16 + (l & 15);
      #pragma unroll
      for (int j = 0; j < 4; ++j) {
        const int row = m0 + wm * 64 + mf * 16 + (l >> 4) * 4 + j;
        float v = acc[mf][nf][j];
        if (EPI == 0) {
          outU[(size_t)row * 768 + col] = f16bits(v);
        } else if (EPI == 1) {
          outF[(size_t)row * 768 + col] = v;
        } else {
          const int b = row >> 12, s = row & 4095;
          const int y = s >> 6, xx = s & 63;
          v += resid[((size_t)(b * 256 + col) << 12) + s];
          outU[((size_t)((b * 66 + 1 + y) * 66) + 1 + xx) * 256 + col] = f16bits(v);
        }
      }
    }
}

// ---------------------------------------------------------------------------
// Batched p-GEMM, single fp16 segment: P[z][s][l] = (Qh·Kh)/sqrt(768).
// z = b*3+h over 12 slices; M=N=4096, K=256.
__global__ __launch_bounds__(256, 2)
void pgemm1(const u16* __restrict__ Qh, const u16* __restrict__ Kh,
            float* __restrict__ P)
{
  __shared__ u16 As[128 * 64];
  __shared__ u16 Bs[128 * 64];
  const int tid = threadIdx.x;
  const int l = tid & 63;
  const int w = tid >> 6;
  const int wm = w >> 1, wn = w & 1;
  const int m0 = blockIdx.x * 128;
  const int n0 = blockIdx.y * 128;
  const int z = blockIdx.z;
  const int bsel = z / 3, hsel = z - bsel * 3;
  const size_t base = (size_t)bsel * 4096 * 768 + hsel * 256;
  float* Pz = P + (size_t)z * 4096 * 4096;

  f32x4 acc[4][4];
  #pragma unroll
  for (int mf = 0; mf < 4; ++mf)
    #pragma unroll
    for (int nf = 0; nf < 4; ++nf) {
      f32x4 zf = {0.f, 0.f, 0.f, 0.f};
      acc[mf][nf] = zf;
    }

  const int srow = tid >> 3;
  const int swz  = (tid & 7) ^ (srow & 7);

  for (int t = 0; t < 4; ++t) {
    const int ci0 = t << 6;
    #pragma unroll
    for (int i = 0; i < 4; ++i) {
      const int pix = i * 32 + srow;
      GLOAD16(Qh + base + (size_t)(m0 + pix) * 768 + ci0 + swz * 8,
              As + (i * 32 + 8 * w) * 64);
      GLOAD16(Kh + base + (size_t)(n0 + pix) * 768 + ci0 + swz * 8,
              Bs + (i * 32 + 8 * w) * 64);
    }
    __syncthreads();

    #pragma unroll
    for (int kk = 0; kk < 2; ++kk) {
      f16x8 av[4], bv[4];
      const int slot = kk * 4 + (l >> 4);
      #pragma unroll
      for (int mf = 0; mf < 4; ++mf) {
        int m = wm * 64 + mf * 16 + (l & 15);
        av[mf] = *(const f16x8*)((const char*)As + m * 128 + ((slot ^ (m & 7)) << 4));
      }
      #pragma unroll
      for (int nf = 0; nf < 4; ++nf) {
        int n = wn * 64 + nf * 16 + (l & 15);
        bv[nf] = *(const f16x8*)((const char*)Bs + n * 128 + ((slot ^ (n & 7)) << 4));
      }
      #pragma unroll
      for (int mf = 0; mf < 4; ++mf)
        #pragma unroll
        for (int nf = 0; nf < 4; ++nf)
          acc[mf][nf] = __builtin_amdgcn_mfma_f32_16x16x32_f16(
              av[mf], bv[nf], acc[mf][nf], 0, 0, 0);
    }
    __syncthreads();
  }

  const float scale = 0.036084391824351615f;   // 1/sqrt(768)
  #pragma unroll
  for (int mf = 0; mf < 4; ++mf)
    #pragma unroll
    for (int nf = 0; nf < 4; ++nf) {
      const int col = n0 + wn * 64 + nf * 16 + (l & 15);
      #pragma unroll
      for (int j = 0; j < 4; ++j) {
        const int row = m0 + wm * 64 + mf * 16 + (l >> 4) * 4 + j;
        Pz[(size_t)row * 4096 + col] = acc[mf][nf][j] * scale;
      }
    }
}

// ---------------------------------------------------------------------------
// Per-row top-16; one wave per row; r = global row in [0, 49152).
// Writes the FULL attn row (zeros + weights) — replaces the 805 MB memset.
// Tier 1 (gap > THRESH): softmax over top-8 into row + tkb pairs, flag=0.
// Tier 2 (tight gap): zero row, 16 candidate indices into tkb, flag=1.
__global__ __launch_bounds__(256)
void topk_softmax(const float* __restrict__ p, float* __restrict__ attn,
                  float* __restrict__ tkb, u32* __restrict__ flagArr)
{
  const int wave = threadIdx.x >> 6;
  const int lane = threadIdx.x & 63;
  const int r = blockIdx.x * 4 + wave;
  const float4* row4 = (const float4*)(p + (size_t)r * 4096);

  float v[8];
  int   id[8];
  #pragma unroll
  for (int t = 0; t < 8; ++t) { v[t] = -INFINITY; id[t] = -1; }

#define TK_INS(val, col)                                                    \
  if ((val) > v[7]) {                                                       \
    v[7] = (val); id[7] = (col);                                            \
    _Pragma("unroll")                                                       \
    for (int t = 7; t >= 1; --t) {                                          \
      if (v[t] > v[t-1]) {                                                  \
        float tv = v[t]; v[t] = v[t-1]; v[t-1] = tv;                        \
        int ti = id[t]; id[t] = id[t-1]; id[t-1] = ti;                      \
      }                                                                     \
    }                                                                       \
  }

  for (int i = 0; i < 16; ++i) {
    float4 q = row4[i * 64 + lane];
    int cb = (i * 64 + lane) * 4;
    TK_INS(q.x, cb + 0)
    TK_INS(q.y, cb + 1)
    TK_INS(q.z, cb + 2)
    TK_INS(q.w, cb + 3)
  }
#undef TK_INS

  // Merge 64 sorted per-lane lists -> global top-16 (all lanes get copies).
  float topv[16];
  int   topi[16];
  int head = 0;
  #pragma unroll
  for (int t = 0; t < 16; ++t) {
    float cand = (head < 8) ? v[head] : -INFINITY;
    float mx = cand; int src = lane;
    #pragma unroll
    for (int off = 32; off >= 1; off >>= 1) {
      float om = __shfl_xor(mx, off);
      int   os = __shfl_xor(src, off);
      if (om > mx || (om == mx && os < src)) { mx = om; src = os; }
    }
    int ci = (head < 8) ? id[head] : -1;
    int wi = __shfl(ci, src);
    if (lane == src) head++;
    topv[t] = mx; topi[t] = wi;
  }

  const float THRESH = 2e-3f;
  unsigned long long exh = __ballot(head >= 8);   // a lane list exhausted (rare)
  const bool flagged = (topv[7] - topv[8] <= THRESH) || (exh != 0ULL);

  float w8[8];
  #pragma unroll
  for (int t = 0; t < 8; ++t) w8[t] = 0.0f;
  if (!flagged) {
    const float m0 = topv[0];
    float den = 0.0f;
    #pragma unroll
    for (int t = 0; t < 8; ++t) den += expf(topv[t] - m0);
    #pragma unroll
    for (int t = 0; t < 8; ++t) w8[t] = expf(topv[t] - m0) / den;
  }

  // Full-row write: zeros with weights merged in-register (no memset pass).
  float4* prow = (float4*)(attn + (size_t)r * 4096);
  #pragma unroll
  for (int i = 0; i < 16; ++i) {
    const int g4 = (i * 64 + lane) << 2;
    float4 f = {0.f, 0.f, 0.f, 0.f};
    if (!flagged) {
      #pragma unroll
      for (int t = 0; t < 8; ++t) {
        f.x = (topi[t] == g4    ) ? w8[t] : f.x;
        f.y = (topi[t] == g4 + 1) ? w8[t] : f.y;
        f.z = (topi[t] == g4 + 2) ? w8[t] : f.z;
        f.w = (topi[t] == g4 + 3) ? w8[t] : f.w;
      }
    }
    prow[i * 64 + lane] = f;
  }

  const size_t grow = (size_t)r;
  if (!flagged) {
    if (lane < 8) {
      tkb[grow * 16 + lane * 2]     = __int_as_float(topi[lane]);
      tkb[grow * 16 + lane * 2 + 1] = w8[lane];
    }
    if (lane == 0) flagArr[grow] = 0;
  } else {
    if (lane < 16) tkb[grow * 16 + lane] = __int_as_float(topi[lane]);
    if (lane == 0) flagArr[grow] = 1;
  }
}

// ---------------------------------------------------------------------------
// Tier-2: exact (float64) rescoring of the 16 candidates for flagged rows,
// recomputed from raw inputs.
__global__ __launch_bounds__(256)
void tier2_fix(const float* __restrict__ x, const float* __restrict__ ref,
               const float* __restrict__ Wq, const float* __restrict__ Wk,
               const u32* __restrict__ flagArr, float* __restrict__ tkb,
               float* __restrict__ attn)
{
  const int row = blockIdx.x;                // slice*4096 + s
  if (flagArr[row] == 0) return;
  const int slice = row >> 12;
  const int s = row & 4095;
  const int b = slice / 3, h = slice % 3;
  const int tid = threadIdx.x;

  __shared__ double redbuf[256];
  __shared__ double qd_s[256];
  __shared__ double u_s[256];
  __shared__ float  xcol[256];
  __shared__ double scores[16];
  __shared__ int    cand[16];

  if (tid < 16) cand[tid] = __float_as_int(tkb[(size_t)row * 16 + tid]);
  xcol[tid] = x[((size_t)(b * 256 + tid) << 12) + s];
  __syncthreads();

  {
    const float* wr = Wq + (size_t)(h * 256 + tid) * 256;
    double acc = 0.0;
    for (int c2 = 0; c2 < 256; ++c2)
      acc = fma((double)wr[c2], (double)xcol[c2], acc);
    qd_s[tid] = acc;
  }
  __syncthreads();

  {
    double acc = 0.0;
    for (int c = 0; c < 256; ++c)
      acc = fma(qd_s[c], (double)Wk[(size_t)(h * 256 + c) * 256 + tid], acc);
    u_s[tid] = acc;
  }
  __syncthreads();

  const double scl = 1.0 / sqrt(768.0);
  for (int t = 0; t < 16; ++t) {
    int ks = cand[t];
    redbuf[tid] = u_s[tid] * (double)ref[((size_t)(b * 256 + tid) << 12) + ks];
    __syncthreads();
    for (int off = 128; off >= 1; off >>= 1) {
      if (tid < off) redbuf[tid] += redbuf[tid + off];
      __syncthreads();
    }
    if (tid == 0) scores[t] = redbuf[0] * scl;
    __syncthreads();
  }

  if (tid == 0) {
    int sel[16];
    for (int i = 0; i < 16; ++i) sel[i] = i;
    for (int i = 0; i < 8; ++i) {
      int best = i;
      for (int j = i + 1; j < 16; ++j)
        if (scores[sel[j]] > scores[sel[best]]) best = j;
      int tmp = sel[i]; sel[i] = sel[best]; sel[best] = tmp;
    }
    double m = scores[sel[0]];
    double e[8], den = 0.0;
    for (int i = 0; i < 8; ++i) { e[i] = exp(scores[sel[i]] - m); den += e[i]; }
    for (int i = 0; i < 8; ++i) {
      int idx = cand[sel[i]];
      float wgt = (float)(e[i] / den);
      attn[(size_t)row * 4096 + idx] = wgt;
      tkb[(size_t)row * 16 + i * 2]     = __int_as_float(idx);
      tkb[(size_t)row * 16 + i * 2 + 1] = wgt;
    }
  }
}

// ---------------------------------------------------------------------------
// Sparse PV: read[b,s,h*256+c] = sum_{t<8} w_t * V[b, idx_t, h*256+c].
// Output as plain fp16 (feeds the 2-seg Wo MFMA GEMM).
__global__ __launch_bounds__(256)
void read_gather(const float* __restrict__ V, const float* __restrict__ tkb,
                 u16* __restrict__ rdH)
{
  const int gr = blockIdx.x;
  const int c  = threadIdx.x;
  const int bh = gr >> 12;
  const int s  = gr & 4095;
  const int b  = bh / 3;
  const int h  = bh % 3;

  __shared__ float wv[8];
  __shared__ int   wi[8];
  if (threadIdx.x < 8) {
    wi[threadIdx.x] = __float_as_int(tkb[(size_t)gr * 16 + threadIdx.x * 2]);
    wv[threadIdx.x] = tkb[(size_t)gr * 16 + threadIdx.x * 2 + 1];
  }
  __syncthreads();

  const float* Vb = V + (size_t)b * 4096 * 768 + h * 256 + c;
  float acc = 0.0f;
  #pragma unroll
  for (int t = 0; t < 8; ++t)
    acc = fmaf(wv[t], Vb[(size_t)wi[t] * 768], acc);
  rdH[((size_t)(b * 4096 + s)) * 768 + h * 256 + c] = f16bits(acc);
}

// ---------------------------------------------------------------------------
// Implicit-GEMM 3x3 conv, fp16 2-seg (A plain fp16, W split => err ~3.5e-4):
// acc = a*w_lo*2^-11 + a*w_hi over K=2*9*256.
// EPI 0: f1 = fp16(selu(acc+bias)) padded. EPI 1: out = acc+bias+resid fp32.
template<int EPI>
__global__ __launch_bounds__(256, 2)
void conv_f16(const u16* __restrict__ in, const u16* __restrict__ Wh,
              const u16* __restrict__ Wl, const float* __restrict__ bias,
              const float* __restrict__ resid, float* __restrict__ outF,
              u16* __restrict__ outU)
{
  __shared__ u16 As[128 * 64];
  __shared__ u16 Bs[128 * 64];
  const int tid = threadIdx.x;
  const int l = tid & 63;
  const int w = tid >> 6;
  const int wm = w >> 1, wn = w & 1;
  const int m0 = blockIdx.x * 128;
  const int n0 = blockIdx.y * 128;
  const int bimg = m0 >> 12;
  const int y0 = (m0 & 4095) >> 6;

  f32x4 acc[4][4];
  #pragma unroll
  for (int mf = 0; mf < 4; ++mf)
    #pragma unroll
    for (int nf = 0; nf < 4; ++nf) {
      f32x4 z = {0.f, 0.f, 0.f, 0.f};
      acc[mf][nf] = z;
    }

  const int srow = tid >> 3;
  const int swz  = (tid & 7) ^ (srow & 7);

  for (int sg = 0; sg < 2; ++sg) {
    const u16* Bw = (sg == 0) ? Wl : Wh;
    for (int d = 0; d < 9; ++d) {
      const int dy = d / 3, dx = d - dy * 3;
      for (int cb = 0; cb < 4; ++cb) {
        const int ci0 = cb << 6;
        #pragma unroll
        for (int i = 0; i < 4; ++i) {
          const int pix = i * 32 + srow;
          const int r = pix >> 6, xx = pix & 63;
          GLOAD16(in + ((size_t)((bimg * 66 + y0 + r + dy) * 66) + dx + xx) * 256
                     + ci0 + swz * 8,
                  As + (i * 32 + 8 * w) * 64);
          const int co = i * 32 + srow;
          GLOAD16(Bw + (size_t)(n0 + co) * 2304 + d * 256 + ci0 + swz * 8,
                  Bs + (i * 32 + 8 * w) * 64);
        }
        __syncthreads();

        #pragma unroll
        for (int kk = 0; kk < 2; ++kk) {
          f16x8 av[4], bv[4];
          const int slot = kk * 4 + (l >> 4);
          #pragma unroll
          for (int mf = 0; mf < 4; ++mf) {
            int m = wm * 64 + mf * 16 + (l & 15);
            av[mf] = *(const f16x8*)((const char*)As + m * 128 + ((slot ^ (m & 7)) << 4));
          }
          #pragma unroll
          for (int nf = 0; nf < 4; ++nf) {
            int n = wn * 64 + nf * 16 + (l & 15);
            bv[nf] = *(const f16x8*)((const char*)Bs + n * 128 + ((slot ^ (n & 7)) << 4));
          }
          #pragma unroll
          for (int mf = 0; mf < 4; ++mf)
            #pragma unroll
            for (int nf = 0; nf < 4; ++nf)
              acc[mf][nf] = __builtin_amdgcn_mfma_f32_16x16x32_f16(
                  av[mf], bv[nf], acc[mf][nf], 0, 0, 0);
        }
        __syncthreads();
      }
    }
    if (sg == 0) {
      #pragma unroll
      for (int mf = 0; mf < 4; ++mf)
        #pragma unroll
        for (int nf = 0; nf < 4; ++nf)
          acc[mf][nf] *= (1.0f / 2048.0f);
    }
  }

  #pragma unroll
  for (int nf = 0; nf < 4; ++nf) {
    const int co = n0 + wn * 64 + nf * 16 + (l & 15);
    const float bvv = bias[co];
    #pragma unroll
    for (int mf = 0; mf < 4; ++mf) {
      #pragma unroll
      for (int j = 0; j < 4; ++j) {
        const int p = m0 + wm * 64 + mf * 16 + (l >> 4) * 4 + j;
        const int y = (p & 4095) >> 6, xx = p & 63;
        float v = acc[mf][nf][j] + bvv;
        if (EPI == 0) {
          v = (v > 0.f) ? 1.0507009873554805f * v
                        : 1.7580993408473766f * expm1f(v);
          outU[((size_t)((bimg * 66 + 1 + y) * 66) + 1 + xx) * 256 + co] = f16bits(v);
        } else {
          size_t ad = ((size_t)(bimg * 256 + co) << 12) + (y << 6) + xx;
          outF[ad] = v + resid[ad];
        }
      }
    }
  }
}

// ---------------------------------------------------------------------------
extern "C" void kernel_launch(void* const* d_in, const int* in_sizes, int n_in,
                              void* d_out, int out_size, void* d_ws, size_t ws_size,
                              hipStream_t stream)
{
  const float* x   = (const float*)d_in[0];
  const float* ref = (const float*)d_in[1];
  const float* Wq  = (const float*)d_in[2];
  const float* Wk  = (const float*)d_in[3];
  const float* Wv  = (const float*)d_in[4];
  const float* Wo  = (const float*)d_in[5];
  const float* c1w = (const float*)d_in[6];
  const float* c1b = (const float*)d_in[7];
  const float* c2w = (const float*)d_in[8];
  const float* c2b = (const float*)d_in[9];

  float* out  = (float*)d_out;                 // [4,256,64,64]
  float* attn = out + 4194304;                 // [12,4096,4096]
  float* ws   = (float*)d_ws;

  // ---- workspace layout (f32 units); ws_size ≈ 3.29 GB per poison fill ----
  u16*   Qh      = (u16*)ws;                     // 16384x768 fp16
  u16*   Kh      = (u16*)(ws + 6291456);
  float* Vb      = ws + 12582912;                // 16384x768 f32
  float* P       = ws + 25165824;                // [49152][4096] f32 (805 MB)
  float* tkb     = ws + 226492416;               // 49152*16
  u32*   flagArr = (u32*)(ws + 227278848);       // 49152
  u16*   xTh     = (u16*)(ws + 227328000);       // 16384x256 fp16 planes
  u16*   xTl     = (u16*)(ws + 229425152);
  u16*   rTh     = (u16*)(ws + 231522304);
  u16*   rTl     = (u16*)(ws + 233619456);
  u16*   WqH     = (u16*)(ws + 235716608);       // 768x256 planes
  u16*   WqL     = (u16*)(ws + 235814912);
  u16*   WkH     = (u16*)(ws + 235913216);
  u16*   WkL     = (u16*)(ws + 236011520);
  u16*   WvH     = (u16*)(ws + 236109824);
  u16*   WvL     = (u16*)(ws + 236208128);
  u16*   WoH     = (u16*)(ws + 236306432);       // 256x768 planes
  u16*   WoL     = (u16*)(ws + 236404736);
  u16*   W1h     = (u16*)(ws + 236503040);       // conv weight planes
  u16*   W1l     = (u16*)(ws + 236797952);
  u16*   W2h     = (u16*)(ws + 237092864);
  u16*   W2l     = (u16*)(ws + 237387776);
  // aliases (dead regions reused):
  u16*   rdH  = (u16*)P;                         // after topk: P dead
  u16*   hHi  = (u16*)ws;                        // after pgemm: Qh dead
  u16*   f1Hi = (u16*)(ws + 6291456);            // after pgemm: Kh dead

  dim3 blk(256);

  // Input transpose+split and weight splits.
  transpose_split<<<dim3(64, 8, 4), blk, 0, stream>>>(x,   xTh, xTl);
  transpose_split<<<dim3(64, 8, 4), blk, 0, stream>>>(ref, rTh, rTl);
  split_plane<<<dim3(768), blk, 0, stream>>>(Wq, WqH, WqL, 196608);
  split_plane<<<dim3(768), blk, 0, stream>>>(Wk, WkH, WkL, 196608);
  split_plane<<<dim3(768), blk, 0, stream>>>(Wv, WvH, WvL, 196608);
  split_plane<<<dim3(768), blk, 0, stream>>>(Wo, WoH, WoL, 196608);
  prep_wt<<<dim3(2304), blk, 0, stream>>>(c1w, c2w, W1h, W1l, W2h, W2l);

  // Projections on matrix cores: Q,K 3-seg (exact-ish, feed the gate); V 2-seg.
  gemm_split<256, 3, 0><<<dim3(128, 6), blk, 0, stream>>>(
      xTh, xTl, WqH, WqL, Qh, nullptr, nullptr);
  gemm_split<256, 3, 0><<<dim3(128, 6), blk, 0, stream>>>(
      rTh, rTl, WkH, WkL, Kh, nullptr, nullptr);
  gemm_split<256, 2, 1><<<dim3(128, 6), blk, 0, stream>>>(
      rTh, nullptr, WvH, WvL, nullptr, Vb, nullptr);

  // Batched single-seg p-GEMM (all 12 slices), then tiered top-k
  // (topk writes full attn rows — no memset of the 805 MB output needed).
  pgemm1<<<dim3(32, 32, 12), blk, 0, stream>>>(Qh, Kh, P);
  topk_softmax<<<dim3(12288), blk, 0, stream>>>(P, attn, tkb, flagArr);

  // Tier-2 exact (f64) fix-up for tight-gap rows.
  tier2_fix<<<dim3(49152), blk, 0, stream>>>(x, ref, Wq, Wk, flagArr, tkb, attn);

  // Sparse PV gather -> read [B,S,768] fp16 (P region is dead now).
  read_gather<<<dim3(49152), blk, 0, stream>>>(Vb, tkb, rdH);

  // Zero padded conv activation halos (Qh/Kh regions dead after pgemm).
  hipMemsetAsync(hHi,  0, (size_t)4460544 * 2, stream);
  hipMemsetAsync(f1Hi, 0, (size_t)4460544 * 2, stream);

  // attn_out = read @ Wo^T + x -> fp16 padded channel-last h (2-seg MFMA).
  gemm_split<768, 2, 2><<<dim3(128, 2), blk, 0, stream>>>(
      rdH, nullptr, WoH, WoL, hHi, nullptr, x);

  // conv1 + SELU -> fp16 padded f1; conv2 + bias + x (outer residual) -> out.
  conv_f16<0><<<dim3(128, 2), blk, 0, stream>>>(hHi, W1h, W1l, c1b,
                                                nullptr, nullptr, f1Hi);
  conv_f16<1><<<dim3(128, 2), blk, 0, stream>>>(f1Hi, W2h, W2l, c2b,
                                                x, out, nullptr);
}

// Round 13
// 1281.162 us; speedup vs baseline: 1.3207x; 1.0619x over previous
//
#include <hip/hip_runtime.h>
#include <math.h>

typedef unsigned short u16;
typedef unsigned int   u32;
typedef __attribute__((ext_vector_type(8))) _Float16 f16x8;  // 8 fp16 (4 VGPRs)
typedef __attribute__((ext_vector_type(4))) float    f32x4;

// fp16 split: v ≈ hi + lo/2048, lo = fp16((v-hi)*2048) stays in normal range.
__device__ __forceinline__ void splitF16(float v, u16& hi, u16& lo) {
  _Float16 h = (_Float16)v;
  _Float16 l = (_Float16)((v - (float)h) * 2048.0f);
  hi = __builtin_bit_cast(u16, h);
  lo = __builtin_bit_cast(u16, l);
}
__device__ __forceinline__ u16 f16bits(float v) {
  _Float16 h = (_Float16)v;
  return __builtin_bit_cast(u16, h);
}

#define GLOAD16(g, l)                                                         \
  __builtin_amdgcn_global_load_lds(                                           \
      (const __attribute__((address_space(1))) void*)(g),                     \
      (__attribute__((address_space(3))) void*)(l), 16, 0, 0)

// ---------------------------------------------------------------------------
// Transpose+split: src [b][256][4096] f32 -> dH/dL [b*4096+s][256] fp16 planes.
// (round-9 proven verbatim)
__global__ __launch_bounds__(256)
void transpose_split(const float* __restrict__ src, u16* __restrict__ dH,
                     u16* __restrict__ dL)
{
  __shared__ float tile[32][65];
  const int b  = blockIdx.z;
  const int s0 = blockIdx.x * 64;
  const int c0 = blockIdx.y * 32;
  const int tid = threadIdx.x;
  const int sl = tid & 63;
  const int cl = (tid >> 6) * 8;
  #pragma unroll
  for (int i = 0; i < 8; ++i)
    tile[cl + i][sl] = src[((size_t)(b * 256 + c0 + cl + i) << 12) + s0 + sl];
  __syncthreads();
  const int sr = tid >> 2;
  const int cc = (tid & 3) * 8;
  union { u16 u[8]; uint4 v; } ph, pl;
  #pragma unroll
  for (int j = 0; j < 8; ++j)
    splitF16(tile[cc + j][sr], ph.u[j], pl.u[j]);
  size_t o = ((size_t)(b * 4096) + s0 + sr) * 256 + c0 + cc;
  *(uint4*)&dH[o] = ph.v;
  *(uint4*)&dL[o] = pl.v;
}

// ---------------------------------------------------------------------------
// Elementwise fp16 split of a weight matrix. (round-9 proven verbatim)
__global__ __launch_bounds__(256)
void split_plane(const float* __restrict__ src, u16* __restrict__ dH,
                 u16* __restrict__ dL, int n)
{
  int i = blockIdx.x * 256 + threadIdx.x;
  if (i < n) { u16 h, l; splitF16(src[i], h, l); dH[i] = h; dL[i] = l; }
}

// ---------------------------------------------------------------------------
// Conv weight prep (CAST-ONLY — the single delta vs round 9):
// Wt[co][d][ci] fp16 <- w[co][ci][d] fp32.
__global__ __launch_bounds__(256)
void prep_wt(const float* __restrict__ w1, const float* __restrict__ w2,
             u16* __restrict__ W1h, u16* __restrict__ W2h)
{
  const int idx = blockIdx.x * 256 + threadIdx.x;
  if (idx >= 256 * 2304) return;
  const int co = idx / 2304;
  const int rem = idx - co * 2304;
  const int d = rem >> 8, ci = rem & 255;
  const int src = (co * 256 + ci) * 9 + d;
  W1h[idx] = f16bits(w1[src]);
  W2h[idx] = f16bits(w2[src]);
}

// ---------------------------------------------------------------------------
// Generic fp16 MFMA GEMM (round-9 proven verbatim; NSEGS 3 and 2 only):
// NSEGS==3: Ah*Bl + Al*Bh (then *2^-11) + Ah*Bh  (fp32-equivalent)
// NSEGS==2: Ah*Bl (then *2^-11) + Ah*Bh          (A plain fp16, B split-exact)
// EPI 0: outU fp16 [m][768]. EPI 1: outF fp32 [m][768].
// EPI 2: h = acc + resid(NCHW) -> fp16 padded channel-last [b][66][66][256].
template<int KD, int NSEGS, int EPI>
__global__ __launch_bounds__(256, 2)
void gemm_split(const u16* __restrict__ Ah, const u16* __restrict__ Al,
                const u16* __restrict__ Bh, const u16* __restrict__ Bl,
                u16* __restrict__ outU, float* __restrict__ outF,
                const float* __restrict__ resid)
{
  __shared__ u16 As[128 * 64];
  __shared__ u16 Bs[128 * 64];
  const int tid = threadIdx.x;
  const int l = tid & 63;
  const int w = tid >> 6;
  const int wm = w >> 1, wn = w & 1;
  const int m0 = blockIdx.x * 128;
  const int n0 = blockIdx.y * 128;

  f32x4 acc[4][4];
  #pragma unroll
  for (int mf = 0; mf < 4; ++mf)
    #pragma unroll
    for (int nf = 0; nf < 4; ++nf) {
      f32x4 z = {0.f, 0.f, 0.f, 0.f};
      acc[mf][nf] = z;
    }

  const int srow = tid >> 3;
  const int swz  = (tid & 7) ^ (srow & 7);
  constexpr int TPS = KD / 64;

  for (int t = 0; t < NSEGS * TPS; ++t) {
    const int sg = t / TPS;
    const int ci0 = (t - sg * TPS) * 64;
    const u16* Ap;
    const u16* Bp;
    if (NSEGS == 3) { Ap = (sg == 1) ? Al : Ah; Bp = (sg == 0) ? Bl : Bh; }
    else            { Ap = Ah;                  Bp = (sg == 0) ? Bl : Bh; }
    #pragma unroll
    for (int i = 0; i < 4; ++i) {
      const int pix = i * 32 + srow;
      GLOAD16(Ap + (size_t)(m0 + pix) * KD + ci0 + swz * 8,
              As + (i * 32 + 8 * w) * 64);
      GLOAD16(Bp + (size_t)(n0 + pix) * KD + ci0 + swz * 8,
              Bs + (i * 32 + 8 * w) * 64);
    }
    __syncthreads();

    #pragma unroll
    for (int kk = 0; kk < 2; ++kk) {
      f16x8 av[4], bv[4];
      const int slot = kk * 4 + (l >> 4);
      #pragma unroll
      for (int mf = 0; mf < 4; ++mf) {
        int m = wm * 64 + mf * 16 + (l & 15);
        av[mf] = *(const f16x8*)((const char*)As + m * 128 + ((slot ^ (m & 7)) << 4));
      }
      #pragma unroll
      for (int nf = 0; nf < 4; ++nf) {
        int n = wn * 64 + nf * 16 + (l & 15);
        bv[nf] = *(const f16x8*)((const char*)Bs + n * 128 + ((slot ^ (n & 7)) << 4));
      }
      #pragma unroll
      for (int mf = 0; mf < 4; ++mf)
        #pragma unroll
        for (int nf = 0; nf < 4; ++nf)
          acc[mf][nf] = __builtin_amdgcn_mfma_f32_16x16x32_f16(
              av[mf], bv[nf], acc[mf][nf], 0, 0, 0);
    }
    __syncthreads();

    if (t == (NSEGS - 1) * TPS - 1) {
      #pragma unroll
      for (int mf = 0; mf < 4; ++mf)
        #pragma unroll
        for (int nf = 0; nf < 4; ++nf)
          acc[mf][nf] *= (1.0f / 2048.0f);
    }
  }

  #pragma unroll
  for (int mf = 0; mf < 4; ++mf)
    #pragma unroll
    for (int nf = 0; nf < 4; ++nf) {
      const int col = n0 + wn * 64 + nf * 16 + (l & 15);
      #pragma unroll
      for (int j = 0; j < 4; ++j) {
        const int row = m0 + wm * 64 + mf * 16 + (l >> 4) * 4 + j;
        float v = acc[mf][nf][j];
        if (EPI == 0) {
          outU[(size_t)row * 768 + col] = f16bits(v);
        } else if (EPI == 1) {
          outF[(size_t)row * 768 + col] = v;
        } else {
          const int b = row >> 12, s = row & 4095;
          const int y = s >> 6, xx = s & 63;
          v += resid[((size_t)(b * 256 + col) << 12) + s];
          outU[((size_t)((b * 66 + 1 + y) * 66) + 1 + xx) * 256 + col] = f16bits(v);
        }
      }
    }
}

// ---------------------------------------------------------------------------
// Batched p-GEMM, single fp16 segment: P[z][s][l] = (Qh·Kh)/sqrt(768), fp32 out.
// (round-9 proven verbatim)
__global__ __launch_bounds__(256, 2)
void pgemm1(const u16* __restrict__ Qh, const u16* __restrict__ Kh,
            float* __restrict__ P)
{
  __shared__ u16 As[128 * 64];
  __shared__ u16 Bs[128 * 64];
  const int tid = threadIdx.x;
  const int l = tid & 63;
  const int w = tid >> 6;
  const int wm = w >> 1, wn = w & 1;
  const int m0 = blockIdx.x * 128;
  const int n0 = blockIdx.y * 128;
  const int z = blockIdx.z;
  const int bsel = z / 3, hsel = z - bsel * 3;
  const size_t base = (size_t)bsel * 4096 * 768 + hsel * 256;
  float* Pz = P + (size_t)z * 4096 * 4096;

  f32x4 acc[4][4];
  #pragma unroll
  for (int mf = 0; mf < 4; ++mf)
    #pragma unroll
    for (int nf = 0; nf < 4; ++nf) {
      f32x4 zf = {0.f, 0.f, 0.f, 0.f};
      acc[mf][nf] = zf;
    }

  const int srow = tid >> 3;
  const int swz  = (tid & 7) ^ (srow & 7);

  for (int t = 0; t < 4; ++t) {
    const int ci0 = t << 6;
    #pragma unroll
    for (int i = 0; i < 4; ++i) {
      const int pix = i * 32 + srow;
      GLOAD16(Qh + base + (size_t)(m0 + pix) * 768 + ci0 + swz * 8,
              As + (i * 32 + 8 * w) * 64);
      GLOAD16(Kh + base + (size_t)(n0 + pix) * 768 + ci0 + swz * 8,
              Bs + (i * 32 + 8 * w) * 64);
    }
    __syncthreads();

    #pragma unroll
    for (int kk = 0; kk < 2; ++kk) {
      f16x8 av[4], bv[4];
      const int slot = kk * 4 + (l >> 4);
      #pragma unroll
      for (int mf = 0; mf < 4; ++mf) {
        int m = wm * 64 + mf * 16 + (l & 15);
        av[mf] = *(const f16x8*)((const char*)As + m * 128 + ((slot ^ (m & 7)) << 4));
      }
      #pragma unroll
      for (int nf = 0; nf < 4; ++nf) {
        int n = wn * 64 + nf * 16 + (l & 15);
        bv[nf] = *(const f16x8*)((const char*)Bs + n * 128 + ((slot ^ (n & 7)) << 4));
      }
      #pragma unroll
      for (int mf = 0; mf < 4; ++mf)
        #pragma unroll
        for (int nf = 0; nf < 4; ++nf)
          acc[mf][nf] = __builtin_amdgcn_mfma_f32_16x16x32_f16(
              av[mf], bv[nf], acc[mf][nf], 0, 0, 0);
    }
    __syncthreads();
  }

  const float scale = 0.036084391824351615f;   // 1/sqrt(768)
  #pragma unroll
  for (int mf = 0; mf < 4; ++mf)
    #pragma unroll
    for (int nf = 0; nf < 4; ++nf) {
      const int col = n0 + wn * 64 + nf * 16 + (l & 15);
      #pragma unroll
      for (int j = 0; j < 4; ++j) {
        const int row = m0 + wm * 64 + mf * 16 + (l >> 4) * 4 + j;
        Pz[(size_t)row * 4096 + col] = acc[mf][nf][j] * scale;
      }
    }
}

// ---------------------------------------------------------------------------
// Per-row top-16 on fp32 P; one wave per row. Writes the FULL attn row.
// (round-9 proven verbatim, THRESH 2e-3)
__global__ __launch_bounds__(256)
void topk_softmax(const float* __restrict__ p, float* __restrict__ attn,
                  float* __restrict__ tkb, u32* __restrict__ flagArr)
{
  const int wave = threadIdx.x >> 6;
  const int lane = threadIdx.x & 63;
  const int r = blockIdx.x * 4 + wave;
  const float4* row4 = (const float4*)(p + (size_t)r * 4096);

  float v[8];
  int   id[8];
  #pragma unroll
  for (int t = 0; t < 8; ++t) { v[t] = -INFINITY; id[t] = -1; }

#define TK_INS(val, col)                                                    \
  if ((val) > v[7]) {                                                       \
    v[7] = (val); id[7] = (col);                                            \
    _Pragma("unroll")                                                       \
    for (int t = 7; t >= 1; --t) {                                          \
      if (v[t] > v[t-1]) {                                                  \
        float tv = v[t]; v[t] = v[t-1]; v[t-1] = tv;                        \
        int ti = id[t]; id[t] = id[t-1]; id[t-1] = ti;                      \
      }                                                                     \
    }                                                                       \
  }

  for (int i = 0; i < 16; ++i) {
    float4 q = row4[i * 64 + lane];
    int cb = (i * 64 + lane) * 4;
    TK_INS(q.x, cb + 0)
    TK_INS(q.y, cb + 1)
    TK_INS(q.z, cb + 2)
    TK_INS(q.w, cb + 3)
  }
#undef TK_INS

  // Merge 64 sorted per-lane lists -> global top-16 (all lanes get copies).
  float topv[16];
  int   topi[16];
  int head = 0;
  #pragma unroll
  for (int t = 0; t < 16; ++t) {
    float cand = (head < 8) ? v[head] : -INFINITY;
    float mx = cand; int src = lane;
    #pragma unroll
    for (int off = 32; off >= 1; off >>= 1) {
      float om = __shfl_xor(mx, off);
      int   os = __shfl_xor(src, off);
      if (om > mx || (om == mx && os < src)) { mx = om; src = os; }
    }
    int ci = (head < 8) ? id[head] : -1;
    int wi = __shfl(ci, src);
    if (lane == src) head++;
    topv[t] = mx; topi[t] = wi;
  }

  const float THRESH = 2e-3f;
  unsigned long long exh = __ballot(head >= 8);   // a lane list exhausted (rare)
  const bool flagged = (topv[7] - topv[8] <= THRESH) || (exh != 0ULL);

  float w8[8];
  #pragma unroll
  for (int t = 0; t < 8; ++t) w8[t] = 0.0f;
  if (!flagged) {
    const float m0 = topv[0];
    float den = 0.0f;
    #pragma unroll
    for (int t = 0; t < 8; ++t) den += expf(topv[t] - m0);
    #pragma unroll
    for (int t = 0; t < 8; ++t) w8[t] = expf(topv[t] - m0) / den;
  }

  // Full-row write: zeros with weights merged in-register (no memset pass).
  float4* prow = (float4*)(attn + (size_t)r * 4096);
  #pragma unroll
  for (int i = 0; i < 16; ++i) {
    const int g4 = (i * 64 + lane) << 2;
    float4 f = {0.f, 0.f, 0.f, 0.f};
    if (!flagged) {
      #pragma unroll
      for (int t = 0; t < 8; ++t) {
        f.x = (topi[t] == g4    ) ? w8[t] : f.x;
        f.y = (topi[t] == g4 + 1) ? w8[t] : f.y;
        f.z = (topi[t] == g4 + 2) ? w8[t] : f.z;
        f.w = (topi[t] == g4 + 3) ? w8[t] : f.w;
      }
    }
    prow[i * 64 + lane] = f;
  }

  const size_t grow = (size_t)r;
  if (!flagged) {
    if (lane < 8) {
      tkb[grow * 16 + lane * 2]     = __int_as_float(topi[lane]);
      tkb[grow * 16 + lane * 2 + 1] = w8[lane];
    }
    if (lane == 0) flagArr[grow] = 0;
  } else {
    if (lane < 16) tkb[grow * 16 + lane] = __int_as_float(topi[lane]);
    if (lane == 0) flagArr[grow] = 1;
  }
}

// ---------------------------------------------------------------------------
// Tier-2: exact (float64) rescoring of the 16 candidates for flagged rows.
// (round-9 proven verbatim)
__global__ __launch_bounds__(256)
void tier2_fix(const float* __restrict__ x, const float* __restrict__ ref,
               const float* __restrict__ Wq, const float* __restrict__ Wk,
               const u32* __restrict__ flagArr, float* __restrict__ tkb,
               float* __restrict__ attn)
{
  const int row = blockIdx.x;                // slice*4096 + s
  if (flagArr[row] == 0) return;
  const int slice = row >> 12;
  const int s = row & 4095;
  const int b = slice / 3, h = slice % 3;
  const int tid = threadIdx.x;

  __shared__ double redbuf[256];
  __shared__ double qd_s[256];
  __shared__ double u_s[256];
  __shared__ float  xcol[256];
  __shared__ double scores[16];
  __shared__ int    cand[16];

  if (tid < 16) cand[tid] = __float_as_int(tkb[(size_t)row * 16 + tid]);
  xcol[tid] = x[((size_t)(b * 256 + tid) << 12) + s];
  __syncthreads();

  {
    const float* wr = Wq + (size_t)(h * 256 + tid) * 256;
    double acc = 0.0;
    for (int c2 = 0; c2 < 256; ++c2)
      acc = fma((double)wr[c2], (double)xcol[c2], acc);
    qd_s[tid] = acc;
  }
  __syncthreads();

  {
    double acc = 0.0;
    for (int c = 0; c < 256; ++c)
      acc = fma(qd_s[c], (double)Wk[(size_t)(h * 256 + c) * 256 + tid], acc);
    u_s[tid] = acc;
  }
  __syncthreads();

  const double scl = 1.0 / sqrt(768.0);
  for (int t = 0; t < 16; ++t) {
    int ks = cand[t];
    redbuf[tid] = u_s[tid] * (double)ref[((size_t)(b * 256 + tid) << 12) + ks];
    __syncthreads();
    for (int off = 128; off >= 1; off >>= 1) {
      if (tid < off) redbuf[tid] += redbuf[tid + off];
      __syncthreads();
    }
    if (tid == 0) scores[t] = redbuf[0] * scl;
    __syncthreads();
  }

  if (tid == 0) {
    int sel[16];
    for (int i = 0; i < 16; ++i) sel[i] = i;
    for (int i = 0; i < 8; ++i) {
      int best = i;
      for (int j = i + 1; j < 16; ++j)
        if (scores[sel[j]] > scores[sel[best]]) best = j;
      int tmp = sel[i]; sel[i] = sel[best]; sel[best] = tmp;
    }
    double m = scores[sel[0]];
    double e[8], den = 0.0;
    for (int i = 0; i < 8; ++i) { e[i] = exp(scores[sel[i]] - m); den += e[i]; }
    for (int i = 0; i < 8; ++i) {
      int idx = cand[sel[i]];
      float wgt = (float)(e[i] / den);
      attn[(size_t)row * 4096 + idx] = wgt;
      tkb[(size_t)row * 16 + i * 2]     = __int_as_float(idx);
      tkb[(size_t)row * 16 + i * 2 + 1] = wgt;
    }
  }
}

// ---------------------------------------------------------------------------
// Sparse PV: read[b,s,h*256+c] = sum_{t<8} w_t * V[b, idx_t, h*256+c].
// (round-9 proven verbatim)
__global__ __launch_bounds__(256)
void read_gather(const float* __restrict__ V, const float* __restrict__ tkb,
                 u16* __restrict__ rdH)
{
  const int gr = blockIdx.x;
  const int c  = threadIdx.x;
  const int bh = gr >> 12;
  const int s  = gr & 4095;
  const int b  = bh / 3;
  const int h  = bh % 3;

  __shared__ float wv[8];
  __shared__ int   wi[8];
  if (threadIdx.x < 8) {
    wi[threadIdx.x] = __float_as_int(tkb[(size_t)gr * 16 + threadIdx.x * 2]);
    wv[threadIdx.x] = tkb[(size_t)gr * 16 + threadIdx.x * 2 + 1];
  }
  __syncthreads();

  const float* Vb = V + (size_t)b * 4096 * 768 + h * 256 + c;
  float acc = 0.0f;
  #pragma unroll
  for (int t = 0; t < 8; ++t)
    acc = fmaf(wv[t], Vb[(size_t)wi[t] * 768], acc);
  rdH[((size_t)(b * 4096 + s)) * 768 + h * 256 + c] = f16bits(acc);
}

// ---------------------------------------------------------------------------
// Implicit-GEMM 3x3 conv, 1-SEG plain fp16 (THE DELTA under test): K=9*256.
// EPI 0: f1 = fp16(selu(acc+bias)) padded. EPI 1: out = acc+bias+resid fp32.
template<int EPI>
__global__ __launch_bounds__(256, 2)
void conv_f16(const u16* __restrict__ in, const u16* __restrict__ Wh,
              const float* __restrict__ bias, const float* __restrict__ resid,
              float* __restrict__ outF, u16* __restrict__ outU)
{
  __shared__ u16 As[128 * 64];
  __shared__ u16 Bs[128 * 64];
  const int tid = threadIdx.x;
  const int l = tid & 63;
  const int w = tid >> 6;
  const int wm = w >> 1, wn = w & 1;
  const int m0 = blockIdx.x * 128;
  const int n0 = blockIdx.y * 128;
  const int bimg = m0 >> 12;
  const int y0 = (m0 & 4095) >> 6;

  f32x4 acc[4][4];
  #pragma unroll
  for (int mf = 0; mf < 4; ++mf)
    #pragma unroll
    for (int nf = 0; nf < 4; ++nf) {
      f32x4 z = {0.f, 0.f, 0.f, 0.f};
      acc[mf][nf] = z;
    }

  const int srow = tid >> 3;
  const int swz  = (tid & 7) ^ (srow & 7);

  for (int d = 0; d < 9; ++d) {
    const int dy = d / 3, dx = d - dy * 3;
    for (int cb = 0; cb < 4; ++cb) {
      const int ci0 = cb << 6;
      #pragma unroll
      for (int i = 0; i < 4; ++i) {
        const int pix = i * 32 + srow;
        const int r = pix >> 6, xx = pix & 63;
        GLOAD16(in + ((size_t)((bimg * 66 + y0 + r + dy) * 66) + dx + xx) * 256
                   + ci0 + swz * 8,
                As + (i * 32 + 8 * w) * 64);
        const int co = i * 32 + srow;
        GLOAD16(Wh + (size_t)(n0 + co) * 2304 + d * 256 + ci0 + swz * 8,
                Bs + (i * 32 + 8 * w) * 64);
      }
      __syncthreads();

      #pragma unroll
      for (int kk = 0; kk < 2; ++kk) {
        f16x8 av[4], bv[4];
        const int slot = kk * 4 + (l >> 4);
        #pragma unroll
        for (int mf = 0; mf < 4; ++mf) {
          int m = wm * 64 + mf * 16 + (l & 15);
          av[mf] = *(const f16x8*)((const char*)As + m * 128 + ((slot ^ (m & 7)) << 4));
        }
        #pragma unroll
        for (int nf = 0; nf < 4; ++nf) {
          int n = wn * 64 + nf * 16 + (l & 15);
          bv[nf] = *(const f16x8*)((const char*)Bs + n * 128 + ((slot ^ (n & 7)) << 4));
        }
        #pragma unroll
        for (int mf = 0; mf < 4; ++mf)
          #pragma unroll
          for (int nf = 0; nf < 4; ++nf)
            acc[mf][nf] = __builtin_amdgcn_mfma_f32_16x16x32_f16(
                av[mf], bv[nf], acc[mf][nf], 0, 0, 0);
      }
      __syncthreads();
    }
  }

  #pragma unroll
  for (int nf = 0; nf < 4; ++nf) {
    const int co = n0 + wn * 64 + nf * 16 + (l & 15);
    const float bvv = bias[co];
    #pragma unroll
    for (int mf = 0; mf < 4; ++mf) {
      #pragma unroll
      for (int j = 0; j < 4; ++j) {
        const int p = m0 + wm * 64 + mf * 16 + (l >> 4) * 4 + j;
        const int y = (p & 4095) >> 6, xx = p & 63;
        float v = acc[mf][nf][j] + bvv;
        if (EPI == 0) {
          v = (v > 0.f) ? 1.0507009873554805f * v
                        : 1.7580993408473766f * expm1f(v);
          outU[((size_t)((bimg * 66 + 1 + y) * 66) + 1 + xx) * 256 + co] = f16bits(v);
        } else {
          size_t ad = ((size_t)(bimg * 256 + co) << 12) + (y << 6) + xx;
          outF[ad] = v + resid[ad];
        }
      }
    }
  }
}

// ---------------------------------------------------------------------------
extern "C" void kernel_launch(void* const* d_in, const int* in_sizes, int n_in,
                              void* d_out, int out_size, void* d_ws, size_t ws_size,
                              hipStream_t stream)
{
  const float* x   = (const float*)d_in[0];
  const float* ref = (const float*)d_in[1];
  const float* Wq  = (const float*)d_in[2];
  const float* Wk  = (const float*)d_in[3];
  const float* Wv  = (const float*)d_in[4];
  const float* Wo  = (const float*)d_in[5];
  const float* c1w = (const float*)d_in[6];
  const float* c1b = (const float*)d_in[7];
  const float* c2w = (const float*)d_in[8];
  const float* c2b = (const float*)d_in[9];

  float* out  = (float*)d_out;                 // [4,256,64,64]
  float* attn = out + 4194304;                 // [12,4096,4096]
  float* ws   = (float*)d_ws;

  // ---- workspace layout: ROUND-9 VERBATIM (f32 offsets) ----
  u16*   Qh      = (u16*)ws;                     // 16384x768 fp16
  u16*   Kh      = (u16*)(ws + 6291456);
  float* Vb      = ws + 12582912;                // 16384x768 f32
  float* P       = ws + 25165824;                // 49152x4096 f32
  float* tkb     = ws + 226492416;               // 49152*16
  u32*   flagArr = (u32*)(ws + 227278848);       // 49152
  u16*   xTh     = (u16*)(ws + 227328000);       // 16384x256 fp16 planes
  u16*   xTl     = (u16*)(ws + 229425152);
  u16*   rTh     = (u16*)(ws + 231522304);
  u16*   rTl     = (u16*)(ws + 233619456);
  u16*   WqH     = (u16*)(ws + 235716608);       // 768x256 planes
  u16*   WqL     = (u16*)(ws + 235814912);
  u16*   WkH     = (u16*)(ws + 235913216);
  u16*   WkL     = (u16*)(ws + 236011520);
  u16*   WvH     = (u16*)(ws + 236109824);
  u16*   WvL     = (u16*)(ws + 236208128);
  u16*   WoH     = (u16*)(ws + 236306432);       // 256x768 planes
  u16*   WoL     = (u16*)(ws + 236404736);
  u16*   W1h     = (u16*)(ws + 236503040);       // conv weight planes
  u16*   W2h     = (u16*)(ws + 237092864);
  // aliases (dead regions reused):
  u16*   rdH  = (u16*)P;                         // after topk/tier2: P dead
  u16*   hHi  = (u16*)ws;                        // after pgemm: Qh dead
  u16*   f1Hi = (u16*)(ws + 6291456);            // after pgemm: Kh dead

  dim3 blk(256);

  // Input transpose+split and weight splits (round-9 verbatim launches).
  transpose_split<<<dim3(64, 8, 4), blk, 0, stream>>>(x,   xTh, xTl);
  transpose_split<<<dim3(64, 8, 4), blk, 0, stream>>>(ref, rTh, rTl);
  split_plane<<<dim3(768), blk, 0, stream>>>(Wq, WqH, WqL, 196608);
  split_plane<<<dim3(768), blk, 0, stream>>>(Wk, WkH, WkL, 196608);
  split_plane<<<dim3(768), blk, 0, stream>>>(Wv, WvH, WvL, 196608);
  split_plane<<<dim3(768), blk, 0, stream>>>(Wo, WoH, WoL, 196608);
  prep_wt<<<dim3(2304), blk, 0, stream>>>(c1w, c2w, W1h, W2h);   // cast-only

  // Projections: Q,K 3-seg fp32-equivalent; V 2-seg (round-9 verbatim).
  gemm_split<256, 3, 0><<<dim3(128, 6), blk, 0, stream>>>(
      xTh, xTl, WqH, WqL, Qh, nullptr, nullptr);
  gemm_split<256, 3, 0><<<dim3(128, 6), blk, 0, stream>>>(
      rTh, rTl, WkH, WkL, Kh, nullptr, nullptr);
  gemm_split<256, 2, 1><<<dim3(128, 6), blk, 0, stream>>>(
      rTh, nullptr, WvH, WvL, nullptr, Vb, nullptr);

  // Batched single-seg p-GEMM -> fp32 P, then tiered top-k (full-row writes).
  pgemm1<<<dim3(32, 32, 12), blk, 0, stream>>>(Qh, Kh, P);
  topk_softmax<<<dim3(12288), blk, 0, stream>>>(P, attn, tkb, flagArr);

  // Tier-2 exact (f64) fix-up for tight-gap rows.
  tier2_fix<<<dim3(49152), blk, 0, stream>>>(x, ref, Wq, Wk, flagArr, tkb, attn);

  // Sparse PV gather -> read [B,S,768] fp16 (P dead now).
  read_gather<<<dim3(49152), blk, 0, stream>>>(Vb, tkb, rdH);

  // Zero padded conv activation halos (Qh/Kh dead after pgemm).
  hipMemsetAsync(hHi,  0, (size_t)4460544 * 2, stream);
  hipMemsetAsync(f1Hi, 0, (size_t)4460544 * 2, stream);

  // attn_out = read @ Wo^T + x -> fp16 padded channel-last h (2-seg, round-9).
  gemm_split<768, 2, 2><<<dim3(128, 2), blk, 0, stream>>>(
      rdH, nullptr, WoH, WoL, hHi, nullptr, x);

  // conv1 + SELU -> fp16 padded f1; conv2 + bias + x -> out  (1-SEG — delta).
  conv_f16<0><<<dim3(128, 2), blk, 0, stream>>>(hHi, W1h, c1b,
                                                nullptr, nullptr, f1Hi);
  conv_f16<1><<<dim3(128, 2), blk, 0, stream>>>(f1Hi, W2h, c2b,
                                                x, out, nullptr);
}